// Round 14
// baseline (67.549 us; speedup 1.0000x reference)
//
#include <hip/hip_runtime.h>
#include <hip/hip_bf16.h>
#include <cmath>

#define BATCH 8
#define ZDIM 512
#define SDIM 256
#define LVL 16
#define TSZ 16384
#define NPIX 65536   // 256*256
#define P2H 2654435761u

typedef __attribute__((ext_vector_type(8))) short bf16x8;
typedef __attribute__((ext_vector_type(4))) float floatx4;
typedef unsigned short ushort_t;

// ws layout per batch (ushort units): 14 A-frags (weightsᵀ), hi at f*1024+lane*8,
// lo at +512.  f=0..3: W0ᵀ m-blocks.  f=4+2m'+kf: W1ᵀ.  f=12+kf: W2ᵀ.
// ch(m,r) = 8*(r>>2)+(r&3)+4*(m&1)+32*(m>>1) baked in (R12-verified).
#define BSTRIDE 14336
// total ws use: 8*14336*2 = 229376 B (proven bound, R5)

// Setup scratch lives in the TAIL of d_out (k_main rewrites all of out after):
// floats, relative to scr = out + out_size - 6144:
//   sbufA @0 [8][256], sbufB @2048 [8][256],
//   modv @4096 [8][32], sc0 @4352 [8][32], sc1 @4608 [8][64], sc2 @5120 [8][64]
#define SCR_SBUFA 0
#define SCR_SBUFB 2048
#define SCR_MODV  4096
#define SCR_SC0   4352
#define SCR_SC1   4608
#define SCR_SC2   5120
#define SCR_TOTAL 6144

__device__ __forceinline__ float lrelu(float x) {
    return (x >= 0.0f ? x : 0.2f * x) * 1.41421356237309515f;
}
__device__ __forceinline__ ushort_t f2bf(float x) {   // RNE f32->bf16
    unsigned u = __builtin_bit_cast(unsigned, x);
    u += 0x7fffu + ((u >> 16) & 1u);
    return (ushort_t)(u >> 16);
}
__device__ __forceinline__ float bf2f(ushort_t h) {
    unsigned u = ((unsigned)h) << 16;
    return __builtin_bit_cast(float, u);
}

struct ResPack { float rm1[LVL]; };

// FC layer: y[b,col] = lrelu(x[b,:] @ w[:,col] + bias[col]).
// grid 32: block j -> cols 8j..8j+7. 256 thr = 8 cols x 8 batches x 4 K-split.
__global__ __launch_bounds__(256) void k_fc(
    const float* __restrict__ x, const float* __restrict__ w,
    const float* __restrict__ bias, float* __restrict__ y, int K)
{
    __shared__ float red[256];
    const int t = threadIdx.x;
    const int c = t & 7, b = (t >> 3) & 7, ks = t >> 6;
    const int col = blockIdx.x * 8 + c;
    const int chunk = K >> 2;
    const float* xb = x + b * K + ks * chunk;
    const float* wp = w + (ks * chunk) * SDIM + col;
    float a0 = 0.f, a1 = 0.f, a2 = 0.f, a3 = 0.f;
#pragma unroll 8
    for (int k = 0; k < chunk; k += 4) {
        a0 = fmaf(xb[k + 0], wp[(k + 0) * SDIM], a0);
        a1 = fmaf(xb[k + 1], wp[(k + 1) * SDIM], a1);
        a2 = fmaf(xb[k + 2], wp[(k + 2) * SDIM], a2);
        a3 = fmaf(xb[k + 3], wp[(k + 3) * SDIM], a3);
    }
    red[t] = (a0 + a1) + (a2 + a3);
    __syncthreads();
    if (ks == 0) {
        const float v = bias[col] + ((red[t] + red[t + 64]) + (red[t + 128] + red[t + 192]));
        y[b * SDIM + col] = lrelu(v);
    }
}

// Scales: modv/sc0 (bx=0), sc1 (bx=1), sc2 (bx=2); grid (3, BATCH).
// 256 thr = 64 outputs x 4 K-split over K=256.
__global__ __launch_bounds__(256) void k_scales(
    const float* __restrict__ gen_w,
    const float* __restrict__ a0w, const float* __restrict__ a0b,
    const float* __restrict__ a1w, const float* __restrict__ a1b,
    const float* __restrict__ a2w, const float* __restrict__ a2b,
    float* __restrict__ scr)
{
    __shared__ float red[256];
    const int t = threadIdx.x, o = t & 63, ks = t >> 6;
    const int b = blockIdx.y, bx = blockIdx.x;
    const float* s = scr + SCR_SBUFA + b * SDIM + ks * 64;

    const float* wp;
    int stride;
    if (bx == 0) {
        if (o < 32) { const int l = o >> 1, f = o & 1; wp = gen_w + l * 512 + f + (ks * 64) * 2; stride = 2; }
        else        { wp = a0w + (o - 32) + (ks * 64) * 32; stride = 32; }
    } else if (bx == 1) { wp = a1w + o + (ks * 64) * 64; stride = 64; }
    else                { wp = a2w + o + (ks * 64) * 64; stride = 64; }

    float a0 = 0.f, a1 = 0.f, a2 = 0.f, a3 = 0.f;
#pragma unroll 8
    for (int k = 0; k < 64; k += 4) {
        a0 = fmaf(s[k + 0], wp[(k + 0) * stride], a0);
        a1 = fmaf(s[k + 1], wp[(k + 1) * stride], a1);
        a2 = fmaf(s[k + 2], wp[(k + 2) * stride], a2);
        a3 = fmaf(s[k + 3], wp[(k + 3) * stride], a3);
    }
    red[t] = (a0 + a1) + (a2 + a3);
    __syncthreads();
    if (ks == 0) {
        const float v = (red[t] + red[t + 64]) + (red[t + 128] + red[t + 192]);
        if (bx == 0) {
            if (o < 32) scr[SCR_MODV + b * 32 + o] = 1.0f + v;
            else        scr[SCR_SC0 + b * 32 + (o - 32)] = a0b[o - 32] + v;
        } else if (bx == 1) scr[SCR_SC1 + b * 64 + o] = a1b[o] + v;
        else                scr[SCR_SC2 + b * 64 + o] = a2b[o] + v;
    }
}

// Pack: demod + effective weights + Wᵀ A-frag packing (R12/R13-verified). grid 8.
__global__ __launch_bounds__(256) void k_pack(
    const float* __restrict__ m0w, const float* __restrict__ m1w,
    const float* __restrict__ m2w,
    const float* __restrict__ scr,
    ushort_t* __restrict__ wsf)
{
    const int b = blockIdx.x;
    const int t = threadIdx.x;
    __shared__ float modv[32], sc0[32], sc1[64], sc2[64];
    __shared__ float d0[64], d1[64], d2[4];
    __shared__ float wl0[32 * 64];
    __shared__ float wl1[64 * 64];
    __shared__ float wl2[64 * 16];

    if (t < 32)       modv[t]      = scr[SCR_MODV + b * 32 + t];
    else if (t < 64)  sc0[t - 32]  = scr[SCR_SC0 + b * 32 + (t - 32)];
    else if (t < 128) sc1[t - 64]  = scr[SCR_SC1 + b * 64 + (t - 64)];
    else if (t < 192) sc2[t - 128] = scr[SCR_SC2 + b * 64 + (t - 128)];
    __syncthreads();

    if (t < 64) {
        float a0 = 0.f, a1 = 0.f, a2 = 0.f, a3 = 0.f;
#pragma unroll 4
        for (int i = 0; i < 32; i += 4) {
            const float v0 = m0w[(i + 0) * 64 + t] * sc0[i + 0];
            const float v1 = m0w[(i + 1) * 64 + t] * sc0[i + 1];
            const float v2 = m0w[(i + 2) * 64 + t] * sc0[i + 2];
            const float v3 = m0w[(i + 3) * 64 + t] * sc0[i + 3];
            a0 = fmaf(v0, v0, a0); a1 = fmaf(v1, v1, a1);
            a2 = fmaf(v2, v2, a2); a3 = fmaf(v3, v3, a3);
        }
        d0[t] = rsqrtf(((a0 + a1) + (a2 + a3)) + 1e-8f);
    } else if (t < 128) {
        const int j = t - 64;
        float a0 = 0.f, a1 = 0.f, a2 = 0.f, a3 = 0.f;
#pragma unroll 4
        for (int i = 0; i < 64; i += 4) {
            const float v0 = m1w[(i + 0) * 64 + j] * sc1[i + 0];
            const float v1 = m1w[(i + 1) * 64 + j] * sc1[i + 1];
            const float v2 = m1w[(i + 2) * 64 + j] * sc1[i + 2];
            const float v3 = m1w[(i + 3) * 64 + j] * sc1[i + 3];
            a0 = fmaf(v0, v0, a0); a1 = fmaf(v1, v1, a1);
            a2 = fmaf(v2, v2, a2); a3 = fmaf(v3, v3, a3);
        }
        d1[j] = rsqrtf(((a0 + a1) + (a2 + a3)) + 1e-8f);
    } else if (t < 131) {
        const int j = t - 128;
        float a0 = 0.f, a1 = 0.f, a2 = 0.f, a3 = 0.f;
#pragma unroll 4
        for (int i = 0; i < 64; i += 4) {
            const float v0 = m2w[(i + 0) * 3 + j] * sc2[i + 0];
            const float v1 = m2w[(i + 1) * 3 + j] * sc2[i + 1];
            const float v2 = m2w[(i + 2) * 3 + j] * sc2[i + 2];
            const float v3 = m2w[(i + 3) * 3 + j] * sc2[i + 3];
            a0 = fmaf(v0, v0, a0); a1 = fmaf(v1, v1, a1);
            a2 = fmaf(v2, v2, a2); a3 = fmaf(v3, v3, a3);
        }
        d2[j] = rsqrtf(((a0 + a1) + (a2 + a3)) + 1e-8f);
    }
    __syncthreads();

    for (int e = t; e < 2048; e += 256) {
        const int i = e >> 6, j = e & 63;
        wl0[e] = m0w[e] * sc0[i] * d0[j] * modv[i];
    }
    for (int e = t; e < 4096; e += 256) {
        const int i = e >> 6, j = e & 63;
        wl1[e] = m1w[e] * sc1[i] * d1[j];
    }
    for (int e = t; e < 1024; e += 256) {
        const int i = e >> 4, j = e & 15;
        wl2[e] = (j < 3) ? m2w[i * 3 + j] * sc2[i] * d2[j] : 0.0f;
    }
    __syncthreads();

    ushort_t* outb = wsf + b * BSTRIDE;
    for (int s = t; s < 896; s += 256) {
        const int f = s >> 6, lane = s & 63;
        const int gg = lane >> 4, cc = lane & 15;   // cc = A row, k = 8*gg+e
        bf16x8 hv, lv;
#pragma unroll
        for (int e = 0; e < 8; ++e) {
            float wv;
            if (f < 4) {
                const int m = f;
                const int ch = 8 * (cc >> 2) + (cc & 3) + 4 * (m & 1) + 32 * (m >> 1);
                wv = wl0[(8 * gg + e) * 64 + ch];
            } else if (f < 12) {
                const int m = (f - 4) >> 1, kf = (f - 4) & 1;
                const int ch = 8 * (cc >> 2) + (cc & 3) + 4 * (m & 1) + 32 * (m >> 1);
                wv = wl1[(32 * kf + 8 * gg + e) * 64 + ch];
            } else {
                const int kf = f - 12;
                wv = wl2[(32 * kf + 8 * gg + e) * 16 + cc];
            }
            const ushort_t hh = f2bf(wv);
            hv[e] = (short)hh;
            lv[e] = (short)f2bf(wv - bf2f(hh));
        }
        *(bf16x8*)(outb + f * 1024 + lane * 8) = hv;
        *(bf16x8*)(outb + f * 1024 + 512 + lane * 8) = lv;
    }
}

// Swapped-operand MFMA chain (R12/R13: passing, byte-identical).
__global__ __launch_bounds__(256) void k_main(
    const float* __restrict__ base_tables,
    const ushort_t* __restrict__ wsf,
    const float* __restrict__ m0b,
    const float* __restrict__ m1b,
    const float* __restrict__ m2b,
    float* __restrict__ out,
    ResPack rp)
{
    const int t = threadIdx.x;
    const int w = t >> 6;
    const int l = t & 63;
    const int g = l >> 4;
    const int c = l & 15;
    const int tile_base = blockIdx.x * 64 + w * 16;

    const int apx = tile_base + c;
    const float cx = ((float)(apx & 255) + 0.5f) * (1.0f / 256.0f);
    const float cy = ((float)(apx >> 8) + 0.5f) * (1.0f / 256.0f);
    bf16x8 rf_hi;
#pragma unroll
    for (int d = 0; d < 4; ++d) {
        float r1 = rp.rm1[d];
        r1 = (g == 1) ? rp.rm1[4 + d] : r1;
        r1 = (g == 2) ? rp.rm1[8 + d] : r1;
        r1 = (g == 3) ? rp.rm1[12 + d] : r1;
        const float sx = cx * r1, sy = cy * r1;
        const float pxf = floorf(sx), pyf = floorf(sy);
        const float fx = sx - pxf, fy = sy - pyf;
        const unsigned x0 = (unsigned)pxf, y0 = (unsigned)pyf;
        const unsigned x1 = x0 + 1u, y1 = y0 + 1u;
        const unsigned hy0 = y0 * P2H, hy1 = y1 * P2H;
        const float2* tab = reinterpret_cast<const float2*>(base_tables) + ((4 * g + d) << 14);
        const float2 f00 = tab[(x0 ^ hy0) & (TSZ - 1)];
        const float2 f01 = tab[(x0 ^ hy1) & (TSZ - 1)];
        const float2 f10 = tab[(x1 ^ hy0) & (TSZ - 1)];
        const float2 f11 = tab[(x1 ^ hy1) & (TSZ - 1)];
        const float w00 = (1.0f - fx) * (1.0f - fy);
        const float w01 = (1.0f - fx) * fy;
        const float w10 = fx * (1.0f - fy);
        const float w11 = fx * fy;
        const float v0 = w00 * f00.x + w01 * f01.x + w10 * f10.x + w11 * f11.x;
        const float v1 = w00 * f00.y + w01 * f01.y + w10 * f10.y + w11 * f11.y;
        rf_hi[2 * d]     = (short)f2bf(v0);
        rf_hi[2 * d + 1] = (short)f2bf(v1);
    }

    float b0v[4][4], b1v[4][4];
#pragma unroll
    for (int m = 0; m < 4; ++m)
#pragma unroll
        for (int q = 0; q < 4; ++q) {
            const int ch = 8 * g + q + 4 * (m & 1) + 32 * (m >> 1);
            b0v[m][q] = m0b[ch];
            b1v[m][q] = m1b[ch];
        }
    const floatx4 acc2init = (g == 0)
        ? (floatx4){ m2b[0], m2b[1], m2b[2], 0.0f }
        : (floatx4){ 0.0f, 0.0f, 0.0f, 0.0f };

#pragma unroll 1
    for (int b = 0; b < BATCH; ++b) {
        const ushort_t* F = wsf + b * BSTRIDE + l * 8;
#define LDF(fi, which) (*(const bf16x8*)(F + (fi) * 1024 + (which) * 512))

        floatx4 acc0[4];
#pragma unroll
        for (int m = 0; m < 4; ++m) {
            acc0[m] = (floatx4){ b0v[m][0], b0v[m][1], b0v[m][2], b0v[m][3] };
            acc0[m] = __builtin_amdgcn_mfma_f32_16x16x32_bf16(LDF(m, 0), rf_hi, acc0[m], 0, 0, 0);
            acc0[m] = __builtin_amdgcn_mfma_f32_16x16x32_bf16(LDF(m, 1), rf_hi, acc0[m], 0, 0, 0);
        }
        bf16x8 h1f0, h1f1;
#pragma unroll
        for (int e = 0; e < 8; ++e) {
            h1f0[e] = (short)f2bf(lrelu(acc0[e >> 2][e & 3]));
            h1f1[e] = (short)f2bf(lrelu(acc0[2 + (e >> 2)][e & 3]));
        }

        floatx4 acc1[4];
#pragma unroll
        for (int m = 0; m < 4; ++m) {
            acc1[m] = (floatx4){ b1v[m][0], b1v[m][1], b1v[m][2], b1v[m][3] };
            acc1[m] = __builtin_amdgcn_mfma_f32_16x16x32_bf16(LDF(4 + 2 * m, 0), h1f0, acc1[m], 0, 0, 0);
            acc1[m] = __builtin_amdgcn_mfma_f32_16x16x32_bf16(LDF(4 + 2 * m, 1), h1f0, acc1[m], 0, 0, 0);
            acc1[m] = __builtin_amdgcn_mfma_f32_16x16x32_bf16(LDF(5 + 2 * m, 0), h1f1, acc1[m], 0, 0, 0);
            acc1[m] = __builtin_amdgcn_mfma_f32_16x16x32_bf16(LDF(5 + 2 * m, 1), h1f1, acc1[m], 0, 0, 0);
        }
        bf16x8 h2f0, h2f1;
#pragma unroll
        for (int e = 0; e < 8; ++e) {
            h2f0[e] = (short)f2bf(lrelu(acc1[e >> 2][e & 3]));
            h2f1[e] = (short)f2bf(lrelu(acc1[2 + (e >> 2)][e & 3]));
        }

        floatx4 acc2 = acc2init;
        acc2 = __builtin_amdgcn_mfma_f32_16x16x32_bf16(LDF(12, 0), h2f0, acc2, 0, 0, 0);
        acc2 = __builtin_amdgcn_mfma_f32_16x16x32_bf16(LDF(12, 1), h2f0, acc2, 0, 0, 0);
        acc2 = __builtin_amdgcn_mfma_f32_16x16x32_bf16(LDF(13, 0), h2f1, acc2, 0, 0, 0);
        acc2 = __builtin_amdgcn_mfma_f32_16x16x32_bf16(LDF(13, 1), h2f1, acc2, 0, 0, 0);

        if (g == 0) {
            out[(b * 3 + 0) * NPIX + tile_base + c] = acc2[0];
            out[(b * 3 + 1) * NPIX + tile_base + c] = acc2[1];
            out[(b * 3 + 2) * NPIX + tile_base + c] = acc2[2];
        }
#undef LDF
    }
}

extern "C" void kernel_launch(void* const* d_in, const int* in_sizes, int n_in,
                              void* d_out, int out_size, void* d_ws, size_t ws_size,
                              hipStream_t stream) {
    const float* z    = (const float*)d_in[0];
    const float* w1   = (const float*)d_in[1];
    const float* b1   = (const float*)d_in[2];
    const float* w2   = (const float*)d_in[3];
    const float* b2   = (const float*)d_in[4];
    const float* w3   = (const float*)d_in[5];
    const float* b3   = (const float*)d_in[6];
    const float* bt   = (const float*)d_in[7];
    const float* genw = (const float*)d_in[8];
    const float* a0w  = (const float*)d_in[9];
    const float* a0b  = (const float*)d_in[10];
    const float* m0w  = (const float*)d_in[11];
    const float* m0b  = (const float*)d_in[12];
    const float* a1w  = (const float*)d_in[13];
    const float* a1b  = (const float*)d_in[14];
    const float* m1w  = (const float*)d_in[15];
    const float* m1b  = (const float*)d_in[16];
    const float* a2w  = (const float*)d_in[17];
    const float* a2b  = (const float*)d_in[18];
    const float* m2w  = (const float*)d_in[19];
    const float* m2b  = (const float*)d_in[20];
    ushort_t* wsf = (ushort_t*)d_ws;
    float* out = (float*)d_out;

    // scratch in the tail of out; k_main rewrites all of out afterwards
    float* scr = out + (out_size - SCR_TOTAL);

    ResPack rp;
    const double bfac = exp((log(256.0) - log(16.0)) / 15.0);
    for (int lv = 0; lv < LVL; ++lv) {
        const double v = floor(16.0 * pow(bfac, (double)lv));
        rp.rm1[lv] = (float)v - 1.0f;
    }

    hipLaunchKernelGGL(k_fc, dim3(32), dim3(256), 0, stream,
                       z, w1, b1, scr + SCR_SBUFA, ZDIM);
    hipLaunchKernelGGL(k_fc, dim3(32), dim3(256), 0, stream,
                       scr + SCR_SBUFA, w2, b2, scr + SCR_SBUFB, SDIM);
    hipLaunchKernelGGL(k_fc, dim3(32), dim3(256), 0, stream,
                       scr + SCR_SBUFB, w3, b3, scr + SCR_SBUFA, SDIM);
    hipLaunchKernelGGL(k_scales, dim3(3, BATCH), dim3(256), 0, stream,
                       genw, a0w, a0b, a1w, a1b, a2w, a2b, scr);
    hipLaunchKernelGGL(k_pack, dim3(BATCH), dim3(256), 0, stream,
                       m0w, m1w, m2w, scr, wsf);
    hipLaunchKernelGGL(k_main, dim3(NPIX / 64), dim3(256), 0, stream,
                       bt, wsf, m0b, m1b, m2b, out, rp);
}

// Round 15
// 52.874 us; speedup vs baseline: 1.2775x; 1.2775x over previous
//
#include <hip/hip_runtime.h>
#include <hip/hip_bf16.h>
#include <cmath>

#define BATCH 8
#define ZDIM 512
#define SDIM 256
#define LVL 16
#define TSZ 16384
#define NPIX 65536   // 256*256
#define P2H 2654435761u

typedef __attribute__((ext_vector_type(8))) short bf16x8;
typedef __attribute__((ext_vector_type(4))) float floatx4;
typedef __attribute__((ext_vector_type(4))) unsigned uintx4;
typedef unsigned short ushort_t;

// ws layout per batch (ushort units): 14 A-frags (weightsᵀ), hi at f*1024+lane*8,
// lo at +512.  f=0..3: W0ᵀ m-blocks.  f=4+2m'+kf: W1ᵀ.  f=12+kf: W2ᵀ.
// ch(m,r) = 8*(r>>2)+(r&3)+4*(m&1)+32*(m>>1) baked in (R12-verified).
#define BSTRIDE 14336
// total ws use: 8*14336*2 = 229376 B (proven bound, R5)

__device__ __forceinline__ float lrelu(float x) {
    return (x >= 0.0f ? x : 0.2f * x) * 1.41421356237309515f;
}
__device__ __forceinline__ ushort_t f2bf(float x) {   // RNE f32->bf16
    unsigned u = __builtin_bit_cast(unsigned, x);
    u += 0x7fffu + ((u >> 16) & 1u);
    return (ushort_t)(u >> 16);
}
__device__ __forceinline__ float bf2f(ushort_t h) {
    unsigned u = ((unsigned)h) << 16;
    return __builtin_bit_cast(float, u);
}
// HW packed f32->bf16 (RNE, identical rounding to f2bf); low16 = a, high16 = b.
__device__ __forceinline__ unsigned cvt_pk_bf16(float a, float b) {
    unsigned r;
    asm("v_cvt_pk_bf16_f32 %0, %1, %2" : "=v"(r) : "v"(a), "v"(b));
    return r;
}

struct ResPack { float rm1[LVL]; };

__global__ __launch_bounds__(256) void k_setup(
    const float* __restrict__ z,
    const float* __restrict__ w1, const float* __restrict__ b1,
    const float* __restrict__ w2, const float* __restrict__ b2,
    const float* __restrict__ w3, const float* __restrict__ b3,
    const float* __restrict__ gen_w,
    const float* __restrict__ a0w, const float* __restrict__ a0b,
    const float* __restrict__ m0w,
    const float* __restrict__ a1w, const float* __restrict__ a1b,
    const float* __restrict__ m1w,
    const float* __restrict__ a2w, const float* __restrict__ a2b,
    const float* __restrict__ m2w,
    ushort_t* __restrict__ wsf)
{
    const int b = blockIdx.x;
    const int t = threadIdx.x;
    __shared__ float sA[SDIM];
    __shared__ float sB[SDIM];
    __shared__ float zb[ZDIM];
    __shared__ float sc0[32], sc1[64], sc2[64], modv[32];
    __shared__ float d0[64], d1[64], d2[4];
    __shared__ float wl0[32 * 64];
    __shared__ float wl1[64 * 64];
    __shared__ float wl2[64 * 16];

    zb[t]       = z[b * ZDIM + t];
    zb[t + 256] = z[b * ZDIM + 256 + t];
    __syncthreads();

    {
        float a0 = 0.f, a1 = 0.f, a2 = 0.f, a3 = 0.f;
#pragma unroll 8
        for (int k = 0; k < ZDIM; k += 4) {
            a0 = fmaf(zb[k + 0], w1[(k + 0) * SDIM + t], a0);
            a1 = fmaf(zb[k + 1], w1[(k + 1) * SDIM + t], a1);
            a2 = fmaf(zb[k + 2], w1[(k + 2) * SDIM + t], a2);
            a3 = fmaf(zb[k + 3], w1[(k + 3) * SDIM + t], a3);
        }
        sA[t] = lrelu(b1[t] + ((a0 + a1) + (a2 + a3)));
    }
    __syncthreads();
    {
        float a0 = 0.f, a1 = 0.f, a2 = 0.f, a3 = 0.f;
#pragma unroll 8
        for (int k = 0; k < SDIM; k += 4) {
            a0 = fmaf(sA[k + 0], w2[(k + 0) * SDIM + t], a0);
            a1 = fmaf(sA[k + 1], w2[(k + 1) * SDIM + t], a1);
            a2 = fmaf(sA[k + 2], w2[(k + 2) * SDIM + t], a2);
            a3 = fmaf(sA[k + 3], w2[(k + 3) * SDIM + t], a3);
        }
        sB[t] = lrelu(b2[t] + ((a0 + a1) + (a2 + a3)));
    }
    __syncthreads();
    {
        float a0 = 0.f, a1 = 0.f, a2 = 0.f, a3 = 0.f;
#pragma unroll 8
        for (int k = 0; k < SDIM; k += 4) {
            a0 = fmaf(sB[k + 0], w3[(k + 0) * SDIM + t], a0);
            a1 = fmaf(sB[k + 1], w3[(k + 1) * SDIM + t], a1);
            a2 = fmaf(sB[k + 2], w3[(k + 2) * SDIM + t], a2);
            a3 = fmaf(sB[k + 3], w3[(k + 3) * SDIM + t], a3);
        }
        sA[t] = lrelu(b3[t] + ((a0 + a1) + (a2 + a3)));
    }
    __syncthreads();

    if (t < 32) {
        const int l = t >> 1, f = t & 1;
        const float* gw = gen_w + l * (SDIM * 2) + f;
        float a0 = 0.f, a1 = 0.f, a2 = 0.f, a3 = 0.f;
#pragma unroll 8
        for (int k = 0; k < SDIM; k += 4) {
            a0 = fmaf(sA[k + 0], gw[(k + 0) * 2], a0);
            a1 = fmaf(sA[k + 1], gw[(k + 1) * 2], a1);
            a2 = fmaf(sA[k + 2], gw[(k + 2) * 2], a2);
            a3 = fmaf(sA[k + 3], gw[(k + 3) * 2], a3);
        }
        modv[t] = 1.0f + ((a0 + a1) + (a2 + a3));
    } else if (t < 64) {
        const int i = t - 32;
        float a0 = 0.f, a1 = 0.f, a2 = 0.f, a3 = 0.f;
#pragma unroll 8
        for (int k = 0; k < SDIM; k += 4) {
            a0 = fmaf(sA[k + 0], a0w[(k + 0) * 32 + i], a0);
            a1 = fmaf(sA[k + 1], a0w[(k + 1) * 32 + i], a1);
            a2 = fmaf(sA[k + 2], a0w[(k + 2) * 32 + i], a2);
            a3 = fmaf(sA[k + 3], a0w[(k + 3) * 32 + i], a3);
        }
        sc0[i] = a0b[i] + ((a0 + a1) + (a2 + a3));
    } else if (t < 128) {
        const int i = t - 64;
        float a0 = 0.f, a1 = 0.f, a2 = 0.f, a3 = 0.f;
#pragma unroll 8
        for (int k = 0; k < SDIM; k += 4) {
            a0 = fmaf(sA[k + 0], a1w[(k + 0) * 64 + i], a0);
            a1 = fmaf(sA[k + 1], a1w[(k + 1) * 64 + i], a1);
            a2 = fmaf(sA[k + 2], a1w[(k + 2) * 64 + i], a2);
            a3 = fmaf(sA[k + 3], a1w[(k + 3) * 64 + i], a3);
        }
        sc1[i] = a1b[i] + ((a0 + a1) + (a2 + a3));
    } else if (t < 192) {
        const int i = t - 128;
        float a0 = 0.f, a1 = 0.f, a2 = 0.f, a3 = 0.f;
#pragma unroll 8
        for (int k = 0; k < SDIM; k += 4) {
            a0 = fmaf(sA[k + 0], a2w[(k + 0) * 64 + i], a0);
            a1 = fmaf(sA[k + 1], a2w[(k + 1) * 64 + i], a1);
            a2 = fmaf(sA[k + 2], a2w[(k + 2) * 64 + i], a2);
            a3 = fmaf(sA[k + 3], a2w[(k + 3) * 64 + i], a3);
        }
        sc2[i] = a2b[i] + ((a0 + a1) + (a2 + a3));
    }
    __syncthreads();

    if (t < 64) {
        float a0 = 0.f, a1 = 0.f, a2 = 0.f, a3 = 0.f;
#pragma unroll 4
        for (int i = 0; i < 32; i += 4) {
            const float v0 = m0w[(i + 0) * 64 + t] * sc0[i + 0];
            const float v1 = m0w[(i + 1) * 64 + t] * sc0[i + 1];
            const float v2 = m0w[(i + 2) * 64 + t] * sc0[i + 2];
            const float v3 = m0w[(i + 3) * 64 + t] * sc0[i + 3];
            a0 = fmaf(v0, v0, a0); a1 = fmaf(v1, v1, a1);
            a2 = fmaf(v2, v2, a2); a3 = fmaf(v3, v3, a3);
        }
        d0[t] = rsqrtf(((a0 + a1) + (a2 + a3)) + 1e-8f);
    } else if (t < 128) {
        const int j = t - 64;
        float a0 = 0.f, a1 = 0.f, a2 = 0.f, a3 = 0.f;
#pragma unroll 4
        for (int i = 0; i < 64; i += 4) {
            const float v0 = m1w[(i + 0) * 64 + j] * sc1[i + 0];
            const float v1 = m1w[(i + 1) * 64 + j] * sc1[i + 1];
            const float v2 = m1w[(i + 2) * 64 + j] * sc1[i + 2];
            const float v3 = m1w[(i + 3) * 64 + j] * sc1[i + 3];
            a0 = fmaf(v0, v0, a0); a1 = fmaf(v1, v1, a1);
            a2 = fmaf(v2, v2, a2); a3 = fmaf(v3, v3, a3);
        }
        d1[j] = rsqrtf(((a0 + a1) + (a2 + a3)) + 1e-8f);
    } else if (t < 131) {
        const int j = t - 128;
        float a0 = 0.f, a1 = 0.f, a2 = 0.f, a3 = 0.f;
#pragma unroll 4
        for (int i = 0; i < 64; i += 4) {
            const float v0 = m2w[(i + 0) * 3 + j] * sc2[i + 0];
            const float v1 = m2w[(i + 1) * 3 + j] * sc2[i + 1];
            const float v2 = m2w[(i + 2) * 3 + j] * sc2[i + 2];
            const float v3 = m2w[(i + 3) * 3 + j] * sc2[i + 3];
            a0 = fmaf(v0, v0, a0); a1 = fmaf(v1, v1, a1);
            a2 = fmaf(v2, v2, a2); a3 = fmaf(v3, v3, a3);
        }
        d2[j] = rsqrtf(((a0 + a1) + (a2 + a3)) + 1e-8f);
    }
    __syncthreads();

    for (int e = t; e < 2048; e += 256) {
        const int i = e >> 6, j = e & 63;
        wl0[e] = m0w[e] * sc0[i] * d0[j] * modv[i];
    }
    for (int e = t; e < 4096; e += 256) {
        const int i = e >> 6, j = e & 63;
        wl1[e] = m1w[e] * sc1[i] * d1[j];
    }
    for (int e = t; e < 1024; e += 256) {
        const int i = e >> 4, j = e & 15;
        wl2[e] = (j < 3) ? m2w[i * 3 + j] * sc2[i] * d2[j] : 0.0f;
    }
    __syncthreads();

    // Pack Wᵀ A-fragments (R12/R13-verified), hi/lo split, ch(m,row) permutation.
    ushort_t* outb = wsf + b * BSTRIDE;
    for (int s = t; s < 896; s += 256) {
        const int f = s >> 6, lane = s & 63;
        const int gg = lane >> 4, cc = lane & 15;   // cc = A row, k = 8*gg+e
        bf16x8 hv, lv;
#pragma unroll
        for (int e = 0; e < 8; ++e) {
            float wv;
            if (f < 4) {
                const int m = f;
                const int ch = 8 * (cc >> 2) + (cc & 3) + 4 * (m & 1) + 32 * (m >> 1);
                wv = wl0[(8 * gg + e) * 64 + ch];
            } else if (f < 12) {
                const int m = (f - 4) >> 1, kf = (f - 4) & 1;
                const int ch = 8 * (cc >> 2) + (cc & 3) + 4 * (m & 1) + 32 * (m >> 1);
                wv = wl1[(32 * kf + 8 * gg + e) * 64 + ch];
            } else {
                const int kf = f - 12;
                wv = wl2[(32 * kf + 8 * gg + e) * 16 + cc];
            }
            const ushort_t hh = f2bf(wv);
            hv[e] = (short)hh;
            lv[e] = (short)f2bf(wv - bf2f(hh));
        }
        *(bf16x8*)(outb + f * 1024 + lane * 8) = hv;
        *(bf16x8*)(outb + f * 1024 + 512 + lane * 8) = lv;
    }
}

// Swapped-operand MFMA chain (R12/R13 passing structure).
// R15 deltas: cvt_pk repack (bit-identical RNE) + W-lo dropped on layer 1.
__global__ __launch_bounds__(256) void k_main(
    const float* __restrict__ base_tables,
    const ushort_t* __restrict__ wsf,
    const float* __restrict__ m0b,
    const float* __restrict__ m1b,
    const float* __restrict__ m2b,
    float* __restrict__ out,
    ResPack rp)
{
    const int t = threadIdx.x;
    const int w = t >> 6;
    const int l = t & 63;
    const int g = l >> 4;
    const int c = l & 15;
    const int tile_base = blockIdx.x * 64 + w * 16;

    const int apx = tile_base + c;
    const float cx = ((float)(apx & 255) + 0.5f) * (1.0f / 256.0f);
    const float cy = ((float)(apx >> 8) + 0.5f) * (1.0f / 256.0f);
    bf16x8 rf_hi;
#pragma unroll
    for (int d = 0; d < 4; ++d) {
        float r1 = rp.rm1[d];
        r1 = (g == 1) ? rp.rm1[4 + d] : r1;
        r1 = (g == 2) ? rp.rm1[8 + d] : r1;
        r1 = (g == 3) ? rp.rm1[12 + d] : r1;
        const float sx = cx * r1, sy = cy * r1;
        const float pxf = floorf(sx), pyf = floorf(sy);
        const float fx = sx - pxf, fy = sy - pyf;
        const unsigned x0 = (unsigned)pxf, y0 = (unsigned)pyf;
        const unsigned x1 = x0 + 1u, y1 = y0 + 1u;
        const unsigned hy0 = y0 * P2H, hy1 = y1 * P2H;
        const float2* tab = reinterpret_cast<const float2*>(base_tables) + ((4 * g + d) << 14);
        const float2 f00 = tab[(x0 ^ hy0) & (TSZ - 1)];
        const float2 f01 = tab[(x0 ^ hy1) & (TSZ - 1)];
        const float2 f10 = tab[(x1 ^ hy0) & (TSZ - 1)];
        const float2 f11 = tab[(x1 ^ hy1) & (TSZ - 1)];
        const float w00 = (1.0f - fx) * (1.0f - fy);
        const float w01 = (1.0f - fx) * fy;
        const float w10 = fx * (1.0f - fy);
        const float w11 = fx * fy;
        const float v0 = w00 * f00.x + w01 * f01.x + w10 * f10.x + w11 * f11.x;
        const float v1 = w00 * f00.y + w01 * f01.y + w10 * f10.y + w11 * f11.y;
        rf_hi[2 * d]     = (short)f2bf(v0);
        rf_hi[2 * d + 1] = (short)f2bf(v1);
    }

    float b0v[4][4], b1v[4][4];
#pragma unroll
    for (int m = 0; m < 4; ++m)
#pragma unroll
        for (int q = 0; q < 4; ++q) {
            const int ch = 8 * g + q + 4 * (m & 1) + 32 * (m >> 1);
            b0v[m][q] = m0b[ch];
            b1v[m][q] = m1b[ch];
        }
    const floatx4 acc2init = (g == 0)
        ? (floatx4){ m2b[0], m2b[1], m2b[2], 0.0f }
        : (floatx4){ 0.0f, 0.0f, 0.0f, 0.0f };

#pragma unroll 1
    for (int b = 0; b < BATCH; ++b) {
        const ushort_t* F = wsf + b * BSTRIDE + l * 8;
#define LDF(fi, which) (*(const bf16x8*)(F + (fi) * 1024 + (which) * 512))

        // ---- layer 0: W hi+lo (full precision on the feature layer)
        floatx4 acc0[4];
#pragma unroll
        for (int m = 0; m < 4; ++m) {
            acc0[m] = (floatx4){ b0v[m][0], b0v[m][1], b0v[m][2], b0v[m][3] };
            acc0[m] = __builtin_amdgcn_mfma_f32_16x16x32_bf16(LDF(m, 0), rf_hi, acc0[m], 0, 0, 0);
            acc0[m] = __builtin_amdgcn_mfma_f32_16x16x32_bf16(LDF(m, 1), rf_hi, acc0[m], 0, 0, 0);
        }
        // lrelu + packed cvt: u[j] = pack(elem 2j, elem 2j+1); elem e = acc[e>>2][e&3]
        uintx4 u0, u1;
#pragma unroll
        for (int j = 0; j < 4; ++j) {
            u0[j] = cvt_pk_bf16(lrelu(acc0[j >> 1][(j & 1) * 2 + 0]),
                                lrelu(acc0[j >> 1][(j & 1) * 2 + 1]));
            u1[j] = cvt_pk_bf16(lrelu(acc0[2 + (j >> 1)][(j & 1) * 2 + 0]),
                                lrelu(acc0[2 + (j >> 1)][(j & 1) * 2 + 1]));
        }
        const bf16x8 h1f0 = __builtin_bit_cast(bf16x8, u0);
        const bf16x8 h1f1 = __builtin_bit_cast(bf16x8, u1);

        // ---- layer 1: W hi only (R15: lo dropped; error budget ~+0.003)
        floatx4 acc1[4];
#pragma unroll
        for (int m = 0; m < 4; ++m) {
            acc1[m] = (floatx4){ b1v[m][0], b1v[m][1], b1v[m][2], b1v[m][3] };
            acc1[m] = __builtin_amdgcn_mfma_f32_16x16x32_bf16(LDF(4 + 2 * m, 0), h1f0, acc1[m], 0, 0, 0);
            acc1[m] = __builtin_amdgcn_mfma_f32_16x16x32_bf16(LDF(5 + 2 * m, 0), h1f1, acc1[m], 0, 0, 0);
        }
        uintx4 v0, v1;
#pragma unroll
        for (int j = 0; j < 4; ++j) {
            v0[j] = cvt_pk_bf16(lrelu(acc1[j >> 1][(j & 1) * 2 + 0]),
                                lrelu(acc1[j >> 1][(j & 1) * 2 + 1]));
            v1[j] = cvt_pk_bf16(lrelu(acc1[2 + (j >> 1)][(j & 1) * 2 + 0]),
                                lrelu(acc1[2 + (j >> 1)][(j & 1) * 2 + 1]));
        }
        const bf16x8 h2f0 = __builtin_bit_cast(bf16x8, v0);
        const bf16x8 h2f1 = __builtin_bit_cast(bf16x8, v1);

        // ---- layer 2: W hi+lo (output layer, keep full precision)
        floatx4 acc2 = acc2init;
        acc2 = __builtin_amdgcn_mfma_f32_16x16x32_bf16(LDF(12, 0), h2f0, acc2, 0, 0, 0);
        acc2 = __builtin_amdgcn_mfma_f32_16x16x32_bf16(LDF(12, 1), h2f0, acc2, 0, 0, 0);
        acc2 = __builtin_amdgcn_mfma_f32_16x16x32_bf16(LDF(13, 0), h2f1, acc2, 0, 0, 0);
        acc2 = __builtin_amdgcn_mfma_f32_16x16x32_bf16(LDF(13, 1), h2f1, acc2, 0, 0, 0);

        if (g == 0) {
            out[(b * 3 + 0) * NPIX + tile_base + c] = acc2[0];
            out[(b * 3 + 1) * NPIX + tile_base + c] = acc2[1];
            out[(b * 3 + 2) * NPIX + tile_base + c] = acc2[2];
        }
#undef LDF
    }
}

extern "C" void kernel_launch(void* const* d_in, const int* in_sizes, int n_in,
                              void* d_out, int out_size, void* d_ws, size_t ws_size,
                              hipStream_t stream) {
    const float* z    = (const float*)d_in[0];
    const float* w1   = (const float*)d_in[1];
    const float* b1   = (const float*)d_in[2];
    const float* w2   = (const float*)d_in[3];
    const float* b2   = (const float*)d_in[4];
    const float* w3   = (const float*)d_in[5];
    const float* b3   = (const float*)d_in[6];
    const float* bt   = (const float*)d_in[7];
    const float* genw = (const float*)d_in[8];
    const float* a0w  = (const float*)d_in[9];
    const float* a0b  = (const float*)d_in[10];
    const float* m0w  = (const float*)d_in[11];
    const float* m0b  = (const float*)d_in[12];
    const float* a1w  = (const float*)d_in[13];
    const float* a1b  = (const float*)d_in[14];
    const float* m1w  = (const float*)d_in[15];
    const float* m1b  = (const float*)d_in[16];
    const float* a2w  = (const float*)d_in[17];
    const float* a2b  = (const float*)d_in[18];
    const float* m2w  = (const float*)d_in[19];
    const float* m2b  = (const float*)d_in[20];
    ushort_t* wsf = (ushort_t*)d_ws;
    float* out = (float*)d_out;

    ResPack rp;
    const double bfac = exp((log(256.0) - log(16.0)) / 15.0);
    for (int lv = 0; lv < LVL; ++lv) {
        const double v = floor(16.0 * pow(bfac, (double)lv));
        rp.rm1[lv] = (float)v - 1.0f;
    }

    hipLaunchKernelGGL(k_setup, dim3(BATCH), dim3(256), 0, stream,
                       z, w1, b1, w2, b2, w3, b3, genw,
                       a0w, a0b, m0w, a1w, a1b, m1w, a2w, a2b, m2w, wsf);

    hipLaunchKernelGGL(k_main, dim3(NPIX / 64), dim3(256), 0, stream,
                       bt, wsf, m0b, m1b, m2b, out, rp);
}

// Round 16
// 47.075 us; speedup vs baseline: 1.4349x; 1.1232x over previous
//
#include <hip/hip_runtime.h>
#include <hip/hip_bf16.h>
#include <cmath>

#define BATCH 8
#define ZDIM 512
#define SDIM 256
#define LVL 16
#define TSZ 16384
#define NPIX 65536   // 256*256
#define P2H 2654435761u

typedef __attribute__((ext_vector_type(8))) short bf16x8;
typedef __attribute__((ext_vector_type(4))) float floatx4;
typedef __attribute__((ext_vector_type(4))) unsigned uintx4;
typedef unsigned short ushort_t;

// ws layout per batch (ushort units): 14 A-frags (weightsᵀ), hi at f*1024+lane*8,
// lo at +512.  f=0..3: W0ᵀ m-blocks.  f=4+2m'+kf: W1ᵀ.  f=12+kf: W2ᵀ.
// ch(m,r) = 8*(r>>2)+(r&3)+4*(m&1)+32*(m>>1) baked in (R12-verified).
#define BSTRIDE 14336
// total ws use: 8*14336*2 = 229376 B (proven bound, R5)

__device__ __forceinline__ float lrelu(float x) {
    return (x >= 0.0f ? x : 0.2f * x) * 1.41421356237309515f;
}
__device__ __forceinline__ ushort_t f2bf(float x) {   // RNE f32->bf16
    unsigned u = __builtin_bit_cast(unsigned, x);
    u += 0x7fffu + ((u >> 16) & 1u);
    return (ushort_t)(u >> 16);
}
__device__ __forceinline__ float bf2f(ushort_t h) {
    unsigned u = ((unsigned)h) << 16;
    return __builtin_bit_cast(float, u);
}
// HW packed f32->bf16 (RNE, identical rounding to f2bf); low16 = a, high16 = b.
__device__ __forceinline__ unsigned cvt_pk_bf16(float a, float b) {
    unsigned r;
    asm("v_cvt_pk_bf16_f32 %0, %1, %2" : "=v"(r) : "v"(a), "v"(b));
    return r;
}

struct ResPack { float rm1[LVL]; };

// 1024-thread k_setup: every GEMV phase 4-way K-split (16 waves/CU -> 4x
// outstanding loads; this kernel is bytes-in-flight latency-bound, R13/R15).
__global__ __launch_bounds__(1024) void k_setup(
    const float* __restrict__ z,
    const float* __restrict__ w1, const float* __restrict__ b1,
    const float* __restrict__ w2, const float* __restrict__ b2,
    const float* __restrict__ w3, const float* __restrict__ b3,
    const float* __restrict__ gen_w,
    const float* __restrict__ a0w, const float* __restrict__ a0b,
    const float* __restrict__ m0w,
    const float* __restrict__ a1w, const float* __restrict__ a1b,
    const float* __restrict__ m1w,
    const float* __restrict__ a2w, const float* __restrict__ a2b,
    const float* __restrict__ m2w,
    ushort_t* __restrict__ wsf)
{
    const int b = blockIdx.x;
    const int t = threadIdx.x;
    __shared__ float red[1024];
    __shared__ float sA[SDIM];
    __shared__ float sB[SDIM];
    __shared__ float zb[ZDIM];
    __shared__ float sc0[32], sc1[64], sc2[64], modv[32];
    __shared__ float d0[64], d1[64], d2[4];
    __shared__ float wl0[32 * 64];
    __shared__ float wl1[64 * 64];
    __shared__ float wl2[64 * 16];

    if (t < ZDIM) zb[t] = z[b * ZDIM + t];
    __syncthreads();

    const int col = t & 255, ks = t >> 8;

    // ---- FC1: [512]->[256], 4-way K-split (chunk 128)
    {
        const float* xb = zb + ks * 128;
        const float* wp = w1 + (ks * 128) * SDIM + col;
        float a0 = 0.f, a1 = 0.f, a2 = 0.f, a3 = 0.f;
#pragma unroll 8
        for (int k = 0; k < 128; k += 4) {
            a0 = fmaf(xb[k + 0], wp[(k + 0) * SDIM], a0);
            a1 = fmaf(xb[k + 1], wp[(k + 1) * SDIM], a1);
            a2 = fmaf(xb[k + 2], wp[(k + 2) * SDIM], a2);
            a3 = fmaf(xb[k + 3], wp[(k + 3) * SDIM], a3);
        }
        red[t] = (a0 + a1) + (a2 + a3);
    }
    __syncthreads();
    if (t < 256)
        sA[t] = lrelu(b1[t] + ((red[t] + red[t + 256]) + (red[t + 512] + red[t + 768])));
    __syncthreads();

    // ---- FC2: [256]->[256], chunk 64
    {
        const float* xb = sA + ks * 64;
        const float* wp = w2 + (ks * 64) * SDIM + col;
        float a0 = 0.f, a1 = 0.f, a2 = 0.f, a3 = 0.f;
#pragma unroll 8
        for (int k = 0; k < 64; k += 4) {
            a0 = fmaf(xb[k + 0], wp[(k + 0) * SDIM], a0);
            a1 = fmaf(xb[k + 1], wp[(k + 1) * SDIM], a1);
            a2 = fmaf(xb[k + 2], wp[(k + 2) * SDIM], a2);
            a3 = fmaf(xb[k + 3], wp[(k + 3) * SDIM], a3);
        }
        red[t] = (a0 + a1) + (a2 + a3);
    }
    __syncthreads();
    if (t < 256)
        sB[t] = lrelu(b2[t] + ((red[t] + red[t + 256]) + (red[t + 512] + red[t + 768])));
    __syncthreads();

    // ---- FC3: [256]->[256], chunk 64 -> final style in sA
    {
        const float* xb = sB + ks * 64;
        const float* wp = w3 + (ks * 64) * SDIM + col;
        float a0 = 0.f, a1 = 0.f, a2 = 0.f, a3 = 0.f;
#pragma unroll 8
        for (int k = 0; k < 64; k += 4) {
            a0 = fmaf(xb[k + 0], wp[(k + 0) * SDIM], a0);
            a1 = fmaf(xb[k + 1], wp[(k + 1) * SDIM], a1);
            a2 = fmaf(xb[k + 2], wp[(k + 2) * SDIM], a2);
            a3 = fmaf(xb[k + 3], wp[(k + 3) * SDIM], a3);
        }
        red[t] = (a0 + a1) + (a2 + a3);
    }
    __syncthreads();
    if (t < 256)
        sA[t] = lrelu(b3[t] + ((red[t] + red[t + 256]) + (red[t + 512] + red[t + 768])));
    __syncthreads();

    // ---- scales (modv/sc0/sc1/sc2): 192 outputs x 4 K-split (chunk 64)
    {
        float r = 0.0f;
        if (col < 192) {
            const float* s = sA + ks * 64;
            const float* wp;
            int stride;
            if (col < 32)       { const int lv = col >> 1, f = col & 1; wp = gen_w + lv * 512 + f + (ks * 64) * 2; stride = 2; }
            else if (col < 64)  { wp = a0w + (col - 32) + (ks * 64) * 32; stride = 32; }
            else if (col < 128) { wp = a1w + (col - 64) + (ks * 64) * 64; stride = 64; }
            else                { wp = a2w + (col - 128) + (ks * 64) * 64; stride = 64; }
            float a0 = 0.f, a1 = 0.f, a2 = 0.f, a3 = 0.f;
#pragma unroll 8
            for (int k = 0; k < 64; k += 4) {
                a0 = fmaf(s[k + 0], wp[(k + 0) * stride], a0);
                a1 = fmaf(s[k + 1], wp[(k + 1) * stride], a1);
                a2 = fmaf(s[k + 2], wp[(k + 2) * stride], a2);
                a3 = fmaf(s[k + 3], wp[(k + 3) * stride], a3);
            }
            r = (a0 + a1) + (a2 + a3);
        }
        red[t] = r;
    }
    __syncthreads();
    if (t < 192) {
        const float v = (red[t] + red[t + 256]) + (red[t + 512] + red[t + 768]);
        if (t < 32)       modv[t] = 1.0f + v;
        else if (t < 64)  sc0[t - 32] = a0b[t - 32] + v;
        else if (t < 128) sc1[t - 64] = a1b[t - 64] + v;
        else              sc2[t - 128] = a2b[t - 128] + v;
    }
    __syncthreads();

    // ---- demod sums: d0 (K=32, chunk 8), d1/d2 (K=64, chunk 16), 4-way split
    {
        float r = 0.0f;
        if (col < 64) {
            float acc = 0.f;
#pragma unroll
            for (int i = ks * 8; i < ks * 8 + 8; ++i) {
                const float v = m0w[i * 64 + col] * sc0[i];
                acc = fmaf(v, v, acc);
            }
            r = acc;
        } else if (col < 128) {
            const int j = col - 64;
            float acc = 0.f;
#pragma unroll
            for (int i = ks * 16; i < ks * 16 + 16; ++i) {
                const float v = m1w[i * 64 + j] * sc1[i];
                acc = fmaf(v, v, acc);
            }
            r = acc;
        } else if (col < 131) {
            const int j = col - 128;
            float acc = 0.f;
#pragma unroll
            for (int i = ks * 16; i < ks * 16 + 16; ++i) {
                const float v = m2w[i * 3 + j] * sc2[i];
                acc = fmaf(v, v, acc);
            }
            r = acc;
        }
        red[t] = r;
    }
    __syncthreads();
    if (t < 131) {
        const float s2 = (red[t] + red[t + 256]) + (red[t + 512] + red[t + 768]);
        if (t < 64)       d0[t] = rsqrtf(s2 + 1e-8f);
        else if (t < 128) d1[t - 64] = rsqrtf(s2 + 1e-8f);
        else              d2[t - 128] = rsqrtf(s2 + 1e-8f);
    }
    __syncthreads();

    // ---- effective weights
    for (int e = t; e < 2048; e += 1024) {
        const int i = e >> 6, j = e & 63;
        wl0[e] = m0w[e] * sc0[i] * d0[j] * modv[i];
    }
    for (int e = t; e < 4096; e += 1024) {
        const int i = e >> 6, j = e & 63;
        wl1[e] = m1w[e] * sc1[i] * d1[j];
    }
    {
        const int i = t >> 4, j = t & 15;
        wl2[t] = (j < 3) ? m2w[i * 3 + j] * sc2[i] * d2[j] : 0.0f;
    }
    __syncthreads();

    // ---- Pack Wᵀ A-fragments (R12/R13-verified layout, byte-identical)
    ushort_t* outb = wsf + b * BSTRIDE;
    if (t < 896) {
        const int f = t >> 6, lane = t & 63;
        const int gg = lane >> 4, cc = lane & 15;   // cc = A row, k = 8*gg+e
        bf16x8 hv, lv;
#pragma unroll
        for (int e = 0; e < 8; ++e) {
            float wv;
            if (f < 4) {
                const int m = f;
                const int ch = 8 * (cc >> 2) + (cc & 3) + 4 * (m & 1) + 32 * (m >> 1);
                wv = wl0[(8 * gg + e) * 64 + ch];
            } else if (f < 12) {
                const int m = (f - 4) >> 1, kf = (f - 4) & 1;
                const int ch = 8 * (cc >> 2) + (cc & 3) + 4 * (m & 1) + 32 * (m >> 1);
                wv = wl1[(32 * kf + 8 * gg + e) * 64 + ch];
            } else {
                const int kf = f - 12;
                wv = wl2[(32 * kf + 8 * gg + e) * 16 + cc];
            }
            const ushort_t hh = f2bf(wv);
            hv[e] = (short)hh;
            lv[e] = (short)f2bf(wv - bf2f(hh));
        }
        *(bf16x8*)(outb + f * 1024 + lane * 8) = hv;
        *(bf16x8*)(outb + f * 1024 + 512 + lane * 8) = lv;
    }
}

// Swapped-operand MFMA chain — byte-identical to R15 (passing).
__global__ __launch_bounds__(256) void k_main(
    const float* __restrict__ base_tables,
    const ushort_t* __restrict__ wsf,
    const float* __restrict__ m0b,
    const float* __restrict__ m1b,
    const float* __restrict__ m2b,
    float* __restrict__ out,
    ResPack rp)
{
    const int t = threadIdx.x;
    const int w = t >> 6;
    const int l = t & 63;
    const int g = l >> 4;
    const int c = l & 15;
    const int tile_base = blockIdx.x * 64 + w * 16;

    const int apx = tile_base + c;
    const float cx = ((float)(apx & 255) + 0.5f) * (1.0f / 256.0f);
    const float cy = ((float)(apx >> 8) + 0.5f) * (1.0f / 256.0f);
    bf16x8 rf_hi;
#pragma unroll
    for (int d = 0; d < 4; ++d) {
        float r1 = rp.rm1[d];
        r1 = (g == 1) ? rp.rm1[4 + d] : r1;
        r1 = (g == 2) ? rp.rm1[8 + d] : r1;
        r1 = (g == 3) ? rp.rm1[12 + d] : r1;
        const float sx = cx * r1, sy = cy * r1;
        const float pxf = floorf(sx), pyf = floorf(sy);
        const float fx = sx - pxf, fy = sy - pyf;
        const unsigned x0 = (unsigned)pxf, y0 = (unsigned)pyf;
        const unsigned x1 = x0 + 1u, y1 = y0 + 1u;
        const unsigned hy0 = y0 * P2H, hy1 = y1 * P2H;
        const float2* tab = reinterpret_cast<const float2*>(base_tables) + ((4 * g + d) << 14);
        const float2 f00 = tab[(x0 ^ hy0) & (TSZ - 1)];
        const float2 f01 = tab[(x0 ^ hy1) & (TSZ - 1)];
        const float2 f10 = tab[(x1 ^ hy0) & (TSZ - 1)];
        const float2 f11 = tab[(x1 ^ hy1) & (TSZ - 1)];
        const float w00 = (1.0f - fx) * (1.0f - fy);
        const float w01 = (1.0f - fx) * fy;
        const float w10 = fx * (1.0f - fy);
        const float w11 = fx * fy;
        const float v0 = w00 * f00.x + w01 * f01.x + w10 * f10.x + w11 * f11.x;
        const float v1 = w00 * f00.y + w01 * f01.y + w10 * f10.y + w11 * f11.y;
        rf_hi[2 * d]     = (short)f2bf(v0);
        rf_hi[2 * d + 1] = (short)f2bf(v1);
    }

    float b0v[4][4], b1v[4][4];
#pragma unroll
    for (int m = 0; m < 4; ++m)
#pragma unroll
        for (int q = 0; q < 4; ++q) {
            const int ch = 8 * g + q + 4 * (m & 1) + 32 * (m >> 1);
            b0v[m][q] = m0b[ch];
            b1v[m][q] = m1b[ch];
        }
    const floatx4 acc2init = (g == 0)
        ? (floatx4){ m2b[0], m2b[1], m2b[2], 0.0f }
        : (floatx4){ 0.0f, 0.0f, 0.0f, 0.0f };

#pragma unroll 1
    for (int b = 0; b < BATCH; ++b) {
        const ushort_t* F = wsf + b * BSTRIDE + l * 8;
#define LDF(fi, which) (*(const bf16x8*)(F + (fi) * 1024 + (which) * 512))

        floatx4 acc0[4];
#pragma unroll
        for (int m = 0; m < 4; ++m) {
            acc0[m] = (floatx4){ b0v[m][0], b0v[m][1], b0v[m][2], b0v[m][3] };
            acc0[m] = __builtin_amdgcn_mfma_f32_16x16x32_bf16(LDF(m, 0), rf_hi, acc0[m], 0, 0, 0);
            acc0[m] = __builtin_amdgcn_mfma_f32_16x16x32_bf16(LDF(m, 1), rf_hi, acc0[m], 0, 0, 0);
        }
        uintx4 u0, u1;
#pragma unroll
        for (int j = 0; j < 4; ++j) {
            u0[j] = cvt_pk_bf16(lrelu(acc0[j >> 1][(j & 1) * 2 + 0]),
                                lrelu(acc0[j >> 1][(j & 1) * 2 + 1]));
            u1[j] = cvt_pk_bf16(lrelu(acc0[2 + (j >> 1)][(j & 1) * 2 + 0]),
                                lrelu(acc0[2 + (j >> 1)][(j & 1) * 2 + 1]));
        }
        const bf16x8 h1f0 = __builtin_bit_cast(bf16x8, u0);
        const bf16x8 h1f1 = __builtin_bit_cast(bf16x8, u1);

        floatx4 acc1[4];
#pragma unroll
        for (int m = 0; m < 4; ++m) {
            acc1[m] = (floatx4){ b1v[m][0], b1v[m][1], b1v[m][2], b1v[m][3] };
            acc1[m] = __builtin_amdgcn_mfma_f32_16x16x32_bf16(LDF(4 + 2 * m, 0), h1f0, acc1[m], 0, 0, 0);
            acc1[m] = __builtin_amdgcn_mfma_f32_16x16x32_bf16(LDF(5 + 2 * m, 0), h1f1, acc1[m], 0, 0, 0);
        }
        uintx4 v0, v1;
#pragma unroll
        for (int j = 0; j < 4; ++j) {
            v0[j] = cvt_pk_bf16(lrelu(acc1[j >> 1][(j & 1) * 2 + 0]),
                                lrelu(acc1[j >> 1][(j & 1) * 2 + 1]));
            v1[j] = cvt_pk_bf16(lrelu(acc1[2 + (j >> 1)][(j & 1) * 2 + 0]),
                                lrelu(acc1[2 + (j >> 1)][(j & 1) * 2 + 1]));
        }
        const bf16x8 h2f0 = __builtin_bit_cast(bf16x8, v0);
        const bf16x8 h2f1 = __builtin_bit_cast(bf16x8, v1);

        floatx4 acc2 = acc2init;
        acc2 = __builtin_amdgcn_mfma_f32_16x16x32_bf16(LDF(12, 0), h2f0, acc2, 0, 0, 0);
        acc2 = __builtin_amdgcn_mfma_f32_16x16x32_bf16(LDF(12, 1), h2f0, acc2, 0, 0, 0);
        acc2 = __builtin_amdgcn_mfma_f32_16x16x32_bf16(LDF(13, 0), h2f1, acc2, 0, 0, 0);
        acc2 = __builtin_amdgcn_mfma_f32_16x16x32_bf16(LDF(13, 1), h2f1, acc2, 0, 0, 0);

        if (g == 0) {
            out[(b * 3 + 0) * NPIX + tile_base + c] = acc2[0];
            out[(b * 3 + 1) * NPIX + tile_base + c] = acc2[1];
            out[(b * 3 + 2) * NPIX + tile_base + c] = acc2[2];
        }
#undef LDF
    }
}

extern "C" void kernel_launch(void* const* d_in, const int* in_sizes, int n_in,
                              void* d_out, int out_size, void* d_ws, size_t ws_size,
                              hipStream_t stream) {
    const float* z    = (const float*)d_in[0];
    const float* w1   = (const float*)d_in[1];
    const float* b1   = (const float*)d_in[2];
    const float* w2   = (const float*)d_in[3];
    const float* b2   = (const float*)d_in[4];
    const float* w3   = (const float*)d_in[5];
    const float* b3   = (const float*)d_in[6];
    const float* bt   = (const float*)d_in[7];
    const float* genw = (const float*)d_in[8];
    const float* a0w  = (const float*)d_in[9];
    const float* a0b  = (const float*)d_in[10];
    const float* m0w  = (const float*)d_in[11];
    const float* m0b  = (const float*)d_in[12];
    const float* a1w  = (const float*)d_in[13];
    const float* a1b  = (const float*)d_in[14];
    const float* m1w  = (const float*)d_in[15];
    const float* m1b  = (const float*)d_in[16];
    const float* a2w  = (const float*)d_in[17];
    const float* a2b  = (const float*)d_in[18];
    const float* m2w  = (const float*)d_in[19];
    const float* m2b  = (const float*)d_in[20];
    ushort_t* wsf = (ushort_t*)d_ws;
    float* out = (float*)d_out;

    ResPack rp;
    const double bfac = exp((log(256.0) - log(16.0)) / 15.0);
    for (int lv = 0; lv < LVL; ++lv) {
        const double v = floor(16.0 * pow(bfac, (double)lv));
        rp.rm1[lv] = (float)v - 1.0f;
    }

    hipLaunchKernelGGL(k_setup, dim3(BATCH), dim3(1024), 0, stream,
                       z, w1, b1, w2, b2, w3, b3, genw,
                       a0w, a0b, m0w, a1w, a1b, m1w, a2w, a2b, m2w, wsf);

    hipLaunchKernelGGL(k_main, dim3(NPIX / 64), dim3(256), 0, stream,
                       bt, wsf, m0b, m1b, m2b, out, rp);
}

// Round 17
// 42.059 us; speedup vs baseline: 1.6060x; 1.1193x over previous
//
#include <hip/hip_runtime.h>
#include <hip/hip_bf16.h>
#include <cmath>

#define BATCH 8
#define ZDIM 512
#define SDIM 256
#define LVL 16
#define TSZ 16384
#define NPIX 65536   // 256*256
#define P2H 2654435761u

typedef __attribute__((ext_vector_type(8))) short bf16x8;
typedef __attribute__((ext_vector_type(4))) float floatx4;
typedef __attribute__((ext_vector_type(4))) unsigned uintx4;
typedef unsigned short ushort_t;

// ws layout per batch (ushort units): 14 A-frags (weightsᵀ), hi at f*1024+lane*8,
// lo at +512.  f=0..3: W0ᵀ m-blocks.  f=4+2m'+kf: W1ᵀ.  f=12+kf: W2ᵀ.
// ch(m,r) = 8*(r>>2)+(r&3)+4*(m&1)+32*(m>>1) baked in (R12-verified).
#define BSTRIDE 14336
// total ws use: 8*14336*2 = 229376 B (proven bound, R5)

__device__ __forceinline__ float lrelu(float x) {
    return (x >= 0.0f ? x : 0.2f * x) * 1.41421356237309515f;
}
__device__ __forceinline__ ushort_t f2bf(float x) {   // RNE f32->bf16
    unsigned u = __builtin_bit_cast(unsigned, x);
    u += 0x7fffu + ((u >> 16) & 1u);
    return (ushort_t)(u >> 16);
}
__device__ __forceinline__ float bf2f(ushort_t h) {
    unsigned u = ((unsigned)h) << 16;
    return __builtin_bit_cast(float, u);
}
// HW packed f32->bf16 (RNE, identical rounding to f2bf); low16 = a, high16 = b.
__device__ __forceinline__ unsigned cvt_pk_bf16(float a, float b) {
    unsigned r;
    asm("v_cvt_pk_bf16_f32 %0, %1, %2" : "=v"(r) : "v"(a), "v"(b));
    return r;
}

struct ResPack { float rm1[LVL]; };

// 1024-thread k_setup (R16: passing, byte-identical).
__global__ __launch_bounds__(1024) void k_setup(
    const float* __restrict__ z,
    const float* __restrict__ w1, const float* __restrict__ b1,
    const float* __restrict__ w2, const float* __restrict__ b2,
    const float* __restrict__ w3, const float* __restrict__ b3,
    const float* __restrict__ gen_w,
    const float* __restrict__ a0w, const float* __restrict__ a0b,
    const float* __restrict__ m0w,
    const float* __restrict__ a1w, const float* __restrict__ a1b,
    const float* __restrict__ m1w,
    const float* __restrict__ a2w, const float* __restrict__ a2b,
    const float* __restrict__ m2w,
    ushort_t* __restrict__ wsf)
{
    const int b = blockIdx.x;
    const int t = threadIdx.x;
    __shared__ float red[1024];
    __shared__ float sA[SDIM];
    __shared__ float sB[SDIM];
    __shared__ float zb[ZDIM];
    __shared__ float sc0[32], sc1[64], sc2[64], modv[32];
    __shared__ float d0[64], d1[64], d2[4];
    __shared__ float wl0[32 * 64];
    __shared__ float wl1[64 * 64];
    __shared__ float wl2[64 * 16];

    if (t < ZDIM) zb[t] = z[b * ZDIM + t];
    __syncthreads();

    const int col = t & 255, ks = t >> 8;

    // ---- FC1: [512]->[256], 4-way K-split (chunk 128)
    {
        const float* xb = zb + ks * 128;
        const float* wp = w1 + (ks * 128) * SDIM + col;
        float a0 = 0.f, a1 = 0.f, a2 = 0.f, a3 = 0.f;
#pragma unroll 8
        for (int k = 0; k < 128; k += 4) {
            a0 = fmaf(xb[k + 0], wp[(k + 0) * SDIM], a0);
            a1 = fmaf(xb[k + 1], wp[(k + 1) * SDIM], a1);
            a2 = fmaf(xb[k + 2], wp[(k + 2) * SDIM], a2);
            a3 = fmaf(xb[k + 3], wp[(k + 3) * SDIM], a3);
        }
        red[t] = (a0 + a1) + (a2 + a3);
    }
    __syncthreads();
    if (t < 256)
        sA[t] = lrelu(b1[t] + ((red[t] + red[t + 256]) + (red[t + 512] + red[t + 768])));
    __syncthreads();

    // ---- FC2: [256]->[256], chunk 64
    {
        const float* xb = sA + ks * 64;
        const float* wp = w2 + (ks * 64) * SDIM + col;
        float a0 = 0.f, a1 = 0.f, a2 = 0.f, a3 = 0.f;
#pragma unroll 8
        for (int k = 0; k < 64; k += 4) {
            a0 = fmaf(xb[k + 0], wp[(k + 0) * SDIM], a0);
            a1 = fmaf(xb[k + 1], wp[(k + 1) * SDIM], a1);
            a2 = fmaf(xb[k + 2], wp[(k + 2) * SDIM], a2);
            a3 = fmaf(xb[k + 3], wp[(k + 3) * SDIM], a3);
        }
        red[t] = (a0 + a1) + (a2 + a3);
    }
    __syncthreads();
    if (t < 256)
        sB[t] = lrelu(b2[t] + ((red[t] + red[t + 256]) + (red[t + 512] + red[t + 768])));
    __syncthreads();

    // ---- FC3: [256]->[256], chunk 64 -> final style in sA
    {
        const float* xb = sB + ks * 64;
        const float* wp = w3 + (ks * 64) * SDIM + col;
        float a0 = 0.f, a1 = 0.f, a2 = 0.f, a3 = 0.f;
#pragma unroll 8
        for (int k = 0; k < 64; k += 4) {
            a0 = fmaf(xb[k + 0], wp[(k + 0) * SDIM], a0);
            a1 = fmaf(xb[k + 1], wp[(k + 1) * SDIM], a1);
            a2 = fmaf(xb[k + 2], wp[(k + 2) * SDIM], a2);
            a3 = fmaf(xb[k + 3], wp[(k + 3) * SDIM], a3);
        }
        red[t] = (a0 + a1) + (a2 + a3);
    }
    __syncthreads();
    if (t < 256)
        sA[t] = lrelu(b3[t] + ((red[t] + red[t + 256]) + (red[t + 512] + red[t + 768])));
    __syncthreads();

    // ---- scales (modv/sc0/sc1/sc2): 192 outputs x 4 K-split (chunk 64)
    {
        float r = 0.0f;
        if (col < 192) {
            const float* s = sA + ks * 64;
            const float* wp;
            int stride;
            if (col < 32)       { const int lv = col >> 1, f = col & 1; wp = gen_w + lv * 512 + f + (ks * 64) * 2; stride = 2; }
            else if (col < 64)  { wp = a0w + (col - 32) + (ks * 64) * 32; stride = 32; }
            else if (col < 128) { wp = a1w + (col - 64) + (ks * 64) * 64; stride = 64; }
            else                { wp = a2w + (col - 128) + (ks * 64) * 64; stride = 64; }
            float a0 = 0.f, a1 = 0.f, a2 = 0.f, a3 = 0.f;
#pragma unroll 8
            for (int k = 0; k < 64; k += 4) {
                a0 = fmaf(s[k + 0], wp[(k + 0) * stride], a0);
                a1 = fmaf(s[k + 1], wp[(k + 1) * stride], a1);
                a2 = fmaf(s[k + 2], wp[(k + 2) * stride], a2);
                a3 = fmaf(s[k + 3], wp[(k + 3) * stride], a3);
            }
            r = (a0 + a1) + (a2 + a3);
        }
        red[t] = r;
    }
    __syncthreads();
    if (t < 192) {
        const float v = (red[t] + red[t + 256]) + (red[t + 512] + red[t + 768]);
        if (t < 32)       modv[t] = 1.0f + v;
        else if (t < 64)  sc0[t - 32] = a0b[t - 32] + v;
        else if (t < 128) sc1[t - 64] = a1b[t - 64] + v;
        else              sc2[t - 128] = a2b[t - 128] + v;
    }
    __syncthreads();

    // ---- demod sums: d0 (K=32, chunk 8), d1/d2 (K=64, chunk 16), 4-way split
    {
        float r = 0.0f;
        if (col < 64) {
            float acc = 0.f;
#pragma unroll
            for (int i = ks * 8; i < ks * 8 + 8; ++i) {
                const float v = m0w[i * 64 + col] * sc0[i];
                acc = fmaf(v, v, acc);
            }
            r = acc;
        } else if (col < 128) {
            const int j = col - 64;
            float acc = 0.f;
#pragma unroll
            for (int i = ks * 16; i < ks * 16 + 16; ++i) {
                const float v = m1w[i * 64 + j] * sc1[i];
                acc = fmaf(v, v, acc);
            }
            r = acc;
        } else if (col < 131) {
            const int j = col - 128;
            float acc = 0.f;
#pragma unroll
            for (int i = ks * 16; i < ks * 16 + 16; ++i) {
                const float v = m2w[i * 3 + j] * sc2[i];
                acc = fmaf(v, v, acc);
            }
            r = acc;
        }
        red[t] = r;
    }
    __syncthreads();
    if (t < 131) {
        const float s2 = (red[t] + red[t + 256]) + (red[t + 512] + red[t + 768]);
        if (t < 64)       d0[t] = rsqrtf(s2 + 1e-8f);
        else if (t < 128) d1[t - 64] = rsqrtf(s2 + 1e-8f);
        else              d2[t - 128] = rsqrtf(s2 + 1e-8f);
    }
    __syncthreads();

    // ---- effective weights
    for (int e = t; e < 2048; e += 1024) {
        const int i = e >> 6, j = e & 63;
        wl0[e] = m0w[e] * sc0[i] * d0[j] * modv[i];
    }
    for (int e = t; e < 4096; e += 1024) {
        const int i = e >> 6, j = e & 63;
        wl1[e] = m1w[e] * sc1[i] * d1[j];
    }
    {
        const int i = t >> 4, j = t & 15;
        wl2[t] = (j < 3) ? m2w[i * 3 + j] * sc2[i] * d2[j] : 0.0f;
    }
    __syncthreads();

    // ---- Pack Wᵀ A-fragments (R12/R13-verified layout, byte-identical)
    ushort_t* outb = wsf + b * BSTRIDE;
    if (t < 896) {
        const int f = t >> 6, lane = t & 63;
        const int gg = lane >> 4, cc = lane & 15;   // cc = A row, k = 8*gg+e
        bf16x8 hv, lv;
#pragma unroll
        for (int e = 0; e < 8; ++e) {
            float wv;
            if (f < 4) {
                const int m = f;
                const int ch = 8 * (cc >> 2) + (cc & 3) + 4 * (m & 1) + 32 * (m >> 1);
                wv = wl0[(8 * gg + e) * 64 + ch];
            } else if (f < 12) {
                const int m = (f - 4) >> 1, kf = (f - 4) & 1;
                const int ch = 8 * (cc >> 2) + (cc & 3) + 4 * (m & 1) + 32 * (m >> 1);
                wv = wl1[(32 * kf + 8 * gg + e) * 64 + ch];
            } else {
                const int kf = f - 12;
                wv = wl2[(32 * kf + 8 * gg + e) * 16 + cc];
            }
            const ushort_t hh = f2bf(wv);
            hv[e] = (short)hh;
            lv[e] = (short)f2bf(wv - bf2f(hh));
        }
        *(bf16x8*)(outb + f * 1024 + lane * 8) = hv;
        *(bf16x8*)(outb + f * 1024 + 512 + lane * 8) = lv;
    }
}

// Swapped-operand MFMA chain (R12/R15 passing structure).
// R17 deltas: W hi-only on ALL layers (14 loads+MFMAs/batch) + unroll-2
// batch loop (prefetch next batch's frags under current compute).
__global__ __launch_bounds__(256) void k_main(
    const float* __restrict__ base_tables,
    const ushort_t* __restrict__ wsf,
    const float* __restrict__ m0b,
    const float* __restrict__ m1b,
    const float* __restrict__ m2b,
    float* __restrict__ out,
    ResPack rp)
{
    const int t = threadIdx.x;
    const int w = t >> 6;
    const int l = t & 63;
    const int g = l >> 4;
    const int c = l & 15;
    const int tile_base = blockIdx.x * 64 + w * 16;

    const int apx = tile_base + c;
    const float cx = ((float)(apx & 255) + 0.5f) * (1.0f / 256.0f);
    const float cy = ((float)(apx >> 8) + 0.5f) * (1.0f / 256.0f);
    bf16x8 rf_hi;
#pragma unroll
    for (int d = 0; d < 4; ++d) {
        float r1 = rp.rm1[d];
        r1 = (g == 1) ? rp.rm1[4 + d] : r1;
        r1 = (g == 2) ? rp.rm1[8 + d] : r1;
        r1 = (g == 3) ? rp.rm1[12 + d] : r1;
        const float sx = cx * r1, sy = cy * r1;
        const float pxf = floorf(sx), pyf = floorf(sy);
        const float fx = sx - pxf, fy = sy - pyf;
        const unsigned x0 = (unsigned)pxf, y0 = (unsigned)pyf;
        const unsigned x1 = x0 + 1u, y1 = y0 + 1u;
        const unsigned hy0 = y0 * P2H, hy1 = y1 * P2H;
        const float2* tab = reinterpret_cast<const float2*>(base_tables) + ((4 * g + d) << 14);
        const float2 f00 = tab[(x0 ^ hy0) & (TSZ - 1)];
        const float2 f01 = tab[(x0 ^ hy1) & (TSZ - 1)];
        const float2 f10 = tab[(x1 ^ hy0) & (TSZ - 1)];
        const float2 f11 = tab[(x1 ^ hy1) & (TSZ - 1)];
        const float w00 = (1.0f - fx) * (1.0f - fy);
        const float w01 = (1.0f - fx) * fy;
        const float w10 = fx * (1.0f - fy);
        const float w11 = fx * fy;
        const float v0 = w00 * f00.x + w01 * f01.x + w10 * f10.x + w11 * f11.x;
        const float v1 = w00 * f00.y + w01 * f01.y + w10 * f10.y + w11 * f11.y;
        rf_hi[2 * d]     = (short)f2bf(v0);
        rf_hi[2 * d + 1] = (short)f2bf(v1);
    }

    float b0v[4][4], b1v[4][4];
#pragma unroll
    for (int m = 0; m < 4; ++m)
#pragma unroll
        for (int q = 0; q < 4; ++q) {
            const int ch = 8 * g + q + 4 * (m & 1) + 32 * (m >> 1);
            b0v[m][q] = m0b[ch];
            b1v[m][q] = m1b[ch];
        }
    const floatx4 acc2init = (g == 0)
        ? (floatx4){ m2b[0], m2b[1], m2b[2], 0.0f }
        : (floatx4){ 0.0f, 0.0f, 0.0f, 0.0f };

#pragma unroll 2
    for (int b = 0; b < BATCH; ++b) {
        const ushort_t* F = wsf + b * BSTRIDE + l * 8;
#define LDF(fi, which) (*(const bf16x8*)(F + (fi) * 1024 + (which) * 512))

        // ---- layer 0: W hi only (R17)
        floatx4 acc0[4];
#pragma unroll
        for (int m = 0; m < 4; ++m) {
            acc0[m] = (floatx4){ b0v[m][0], b0v[m][1], b0v[m][2], b0v[m][3] };
            acc0[m] = __builtin_amdgcn_mfma_f32_16x16x32_bf16(LDF(m, 0), rf_hi, acc0[m], 0, 0, 0);
        }
        uintx4 u0, u1;
#pragma unroll
        for (int j = 0; j < 4; ++j) {
            u0[j] = cvt_pk_bf16(lrelu(acc0[j >> 1][(j & 1) * 2 + 0]),
                                lrelu(acc0[j >> 1][(j & 1) * 2 + 1]));
            u1[j] = cvt_pk_bf16(lrelu(acc0[2 + (j >> 1)][(j & 1) * 2 + 0]),
                                lrelu(acc0[2 + (j >> 1)][(j & 1) * 2 + 1]));
        }
        const bf16x8 h1f0 = __builtin_bit_cast(bf16x8, u0);
        const bf16x8 h1f1 = __builtin_bit_cast(bf16x8, u1);

        // ---- layer 1: W hi only (R15)
        floatx4 acc1[4];
#pragma unroll
        for (int m = 0; m < 4; ++m) {
            acc1[m] = (floatx4){ b1v[m][0], b1v[m][1], b1v[m][2], b1v[m][3] };
            acc1[m] = __builtin_amdgcn_mfma_f32_16x16x32_bf16(LDF(4 + 2 * m, 0), h1f0, acc1[m], 0, 0, 0);
            acc1[m] = __builtin_amdgcn_mfma_f32_16x16x32_bf16(LDF(5 + 2 * m, 0), h1f1, acc1[m], 0, 0, 0);
        }
        uintx4 v0, v1;
#pragma unroll
        for (int j = 0; j < 4; ++j) {
            v0[j] = cvt_pk_bf16(lrelu(acc1[j >> 1][(j & 1) * 2 + 0]),
                                lrelu(acc1[j >> 1][(j & 1) * 2 + 1]));
            v1[j] = cvt_pk_bf16(lrelu(acc1[2 + (j >> 1)][(j & 1) * 2 + 0]),
                                lrelu(acc1[2 + (j >> 1)][(j & 1) * 2 + 1]));
        }
        const bf16x8 h2f0 = __builtin_bit_cast(bf16x8, v0);
        const bf16x8 h2f1 = __builtin_bit_cast(bf16x8, v1);

        // ---- layer 2: W hi only (R17)
        floatx4 acc2 = acc2init;
        acc2 = __builtin_amdgcn_mfma_f32_16x16x32_bf16(LDF(12, 0), h2f0, acc2, 0, 0, 0);
        acc2 = __builtin_amdgcn_mfma_f32_16x16x32_bf16(LDF(13, 0), h2f1, acc2, 0, 0, 0);

        if (g == 0) {
            out[(b * 3 + 0) * NPIX + tile_base + c] = acc2[0];
            out[(b * 3 + 1) * NPIX + tile_base + c] = acc2[1];
            out[(b * 3 + 2) * NPIX + tile_base + c] = acc2[2];
        }
#undef LDF
    }
}

extern "C" void kernel_launch(void* const* d_in, const int* in_sizes, int n_in,
                              void* d_out, int out_size, void* d_ws, size_t ws_size,
                              hipStream_t stream) {
    const float* z    = (const float*)d_in[0];
    const float* w1   = (const float*)d_in[1];
    const float* b1   = (const float*)d_in[2];
    const float* w2   = (const float*)d_in[3];
    const float* b2   = (const float*)d_in[4];
    const float* w3   = (const float*)d_in[5];
    const float* b3   = (const float*)d_in[6];
    const float* bt   = (const float*)d_in[7];
    const float* genw = (const float*)d_in[8];
    const float* a0w  = (const float*)d_in[9];
    const float* a0b  = (const float*)d_in[10];
    const float* m0w  = (const float*)d_in[11];
    const float* m0b  = (const float*)d_in[12];
    const float* a1w  = (const float*)d_in[13];
    const float* a1b  = (const float*)d_in[14];
    const float* m1w  = (const float*)d_in[15];
    const float* m1b  = (const float*)d_in[16];
    const float* a2w  = (const float*)d_in[17];
    const float* a2b  = (const float*)d_in[18];
    const float* m2w  = (const float*)d_in[19];
    const float* m2b  = (const float*)d_in[20];
    ushort_t* wsf = (ushort_t*)d_ws;
    float* out = (float*)d_out;

    ResPack rp;
    const double bfac = exp((log(256.0) - log(16.0)) / 15.0);
    for (int lv = 0; lv < LVL; ++lv) {
        const double v = floor(16.0 * pow(bfac, (double)lv));
        rp.rm1[lv] = (float)v - 1.0f;
    }

    hipLaunchKernelGGL(k_setup, dim3(BATCH), dim3(1024), 0, stream,
                       z, w1, b1, w2, b2, w3, b3, genw,
                       a0w, a0b, m0w, a1w, a1b, m1w, a2w, a2b, m2w, wsf);

    hipLaunchKernelGGL(k_main, dim3(NPIX / 64), dim3(256), 0, stream,
                       bt, wsf, m0b, m1b, m2b, out, rp);
}